// Round 2
// baseline (300.024 us; speedup 1.0000x reference)
//
#include <hip/hip_runtime.h>

#define POOL 7
#define PP   (POOL * POOL)

// ---------------------------------------------------------------------------
// Kernel 1: stable counting sort rank per box within its batch.
// pos[n] = #{m : lvl[m] < lvl[n]} + #{m < n : lvl[m] == lvl[n]}
// One block per batch; N <= 1024 (here N = 1000).
// ---------------------------------------------------------------------------
__global__ void compute_order_kernel(const int* __restrict__ levels,
                                     int* __restrict__ dst, int N) {
    __shared__ int lvl[1024];
    const int b = blockIdx.x;
    const int n = threadIdx.x;
    const int* L = levels + (size_t)b * N;
    if (n < N) lvl[n] = L[n];
    __syncthreads();
    if (n < N) {
        const int my = lvl[n];
        int pos = 0;
        for (int m = 0; m < N; ++m) {
            const int lm = lvl[m];
            pos += (int)((lm < my) | ((lm == my) & (m < n)));
        }
        dst[(size_t)b * N + n] = pos;
    }
}

// ---------------------------------------------------------------------------
// Kernel 2: crop_and_resize (bilinear, extrapolation 0) for the box's FPN
// level, writing directly to its sorted output slot.
// Grid: one block per box (B*N blocks), 256 threads = 4 waves.
// Each wave processes sample positions pq = wave, wave+4, ... (49 total);
// lane handles 4 channels (float4).
//
// COORDINATE MATH IS DOUBLE PRECISION. The validity test `in_y <= H-1` is
// discontinuous (valid->0), and boxes clipped at y2==1.0 land within ulps of
// exactly H-1. The harness's np reference evaluates in f64; matching its
// mask decisions requires bit-identical f64 coordinate evaluation (same op
// order as the reference formula). Feature interpolation stays f32.
// ---------------------------------------------------------------------------
__global__ __launch_bounds__(256) void roi_align_kernel(
    const float* __restrict__ boxes,
    const float* __restrict__ fm0, const float* __restrict__ fm1,
    const float* __restrict__ fm2, const float* __restrict__ fm3,
    const int* __restrict__ levels, const int* __restrict__ dst,
    float* __restrict__ out, int N, int C) {

    const int box_flat = blockIdx.x;
    const int wave = threadIdx.x >> 6;
    const int lane = threadIdx.x & 63;
    const int b = box_flat / N;

    const int lv = levels[box_flat] - 1;  // 1..4 -> 0..3
    const float* fm; int S;
    if      (lv == 0) { fm = fm0; S = 256; }
    else if (lv == 1) { fm = fm1; S = 128; }
    else if (lv == 2) { fm = fm2; S = 64;  }
    else              { fm = fm3; S = 32;  }

    const double y1 = (double)boxes[(size_t)box_flat * 4 + 0];
    const double x1 = (double)boxes[(size_t)box_flat * 4 + 1];
    const double y2 = (double)boxes[(size_t)box_flat * 4 + 2];
    const double x2 = (double)boxes[(size_t)box_flat * 4 + 3];

    const double Hm1 = (double)(S - 1);
    // scale = (y2-y1)*(H-1)/(POOL-1), f64, same association as reference.
    const double sy = (y2 - y1) * Hm1 / (double)(POOL - 1);
    const double sx = (x2 - x1) * Hm1 / (double)(POOL - 1);
    const double oy = y1 * Hm1;
    const double ox = x1 * Hm1;

    const int pos = dst[box_flat];
    const float* fmb  = fm  + (size_t)b * S * S * C;
    float*       outb = out + ((size_t)b * N + pos) * PP * C;

    for (int pq = wave; pq < PP; pq += 4) {
        const int gi = pq / POOL;
        const int gj = pq - gi * POOL;

        const double in_y = oy + (double)gi * sy;
        const double in_x = ox + (double)gj * sx;
        const bool valid = (in_y >= 0.0) && (in_y <= Hm1) &&
                           (in_x >= 0.0) && (in_x <= Hm1);

        const double fy = floor(in_y);
        const double fx = floor(in_x);
        const float wy = (float)(in_y - fy);
        const float wx = (float)(in_x - fx);

        const int ty = (int)fmin(fmax(fy, 0.0), Hm1);
        const int by = min(ty + 1, S - 1);
        const int lx = (int)fmin(fmax(fx, 0.0), Hm1);
        const int rx = min(lx + 1, S - 1);

        const float* rowT = fmb + (size_t)ty * S * C;
        const float* rowB = fmb + (size_t)by * S * C;
        float* op = outb + (size_t)pq * C;

        for (int c = lane * 4; c < C; c += 256) {
            const float4 tl = *(const float4*)(rowT + (size_t)lx * C + c);
            const float4 tr = *(const float4*)(rowT + (size_t)rx * C + c);
            const float4 bl = *(const float4*)(rowB + (size_t)lx * C + c);
            const float4 br = *(const float4*)(rowB + (size_t)rx * C + c);

            float4 o;
            {
                float top = tl.x + (tr.x - tl.x) * wx;
                float bot = bl.x + (br.x - bl.x) * wx;
                o.x = top + (bot - top) * wy;
                top = tl.y + (tr.y - tl.y) * wx;
                bot = bl.y + (br.y - bl.y) * wx;
                o.y = top + (bot - top) * wy;
                top = tl.z + (tr.z - tl.z) * wx;
                bot = bl.z + (br.z - bl.z) * wx;
                o.z = top + (bot - top) * wy;
                top = tl.w + (tr.w - tl.w) * wx;
                bot = bl.w + (br.w - bl.w) * wx;
                o.w = top + (bot - top) * wy;
            }
            if (!valid) { o.x = 0.0f; o.y = 0.0f; o.z = 0.0f; o.w = 0.0f; }
            *(float4*)(op + c) = o;
        }
    }
}

extern "C" void kernel_launch(void* const* d_in, const int* in_sizes, int n_in,
                              void* d_out, int out_size, void* d_ws, size_t ws_size,
                              hipStream_t stream) {
    const float* boxes  = (const float*)d_in[0];
    const float* fm0    = (const float*)d_in[1];
    const float* fm1    = (const float*)d_in[2];
    const float* fm2    = (const float*)d_in[3];
    const float* fm3    = (const float*)d_in[4];
    const int*   levels = (const int*)d_in[5];
    float* out = (float*)d_out;

    const int BN = in_sizes[5];              // B*N = 2000
    const int C  = out_size / (BN * PP);     // 256
    const int B  = in_sizes[1] / (256 * 256 * C);  // fm0 is [B,256,256,C]
    const int N  = BN / B;                   // 1000

    int* dst = (int*)d_ws;                   // BN ints of scratch

    compute_order_kernel<<<B, 1024, 0, stream>>>(levels, dst, N);
    roi_align_kernel<<<BN, 256, 0, stream>>>(boxes, fm0, fm1, fm2, fm3,
                                             levels, dst, out, N, C);
}

// Round 3
// 298.865 us; speedup vs baseline: 1.0039x; 1.0039x over previous
//
#include <hip/hip_runtime.h>

#define POOL 7
#define PP   (POOL * POOL)

// ---------------------------------------------------------------------------
// Kernel 1: stable counting sort rank per box within its batch.
// pos[n] = #{m : lvl[m] < lvl[n]} + #{m < n : lvl[m] == lvl[n]}
// One block per batch; N <= 1024 (here N = 1000). ~4 us, not worth tuning.
// ---------------------------------------------------------------------------
__global__ void compute_order_kernel(const int* __restrict__ levels,
                                     int* __restrict__ dst, int N) {
    __shared__ int lvl[1024];
    const int b = blockIdx.x;
    const int n = threadIdx.x;
    const int* L = levels + (size_t)b * N;
    if (n < N) lvl[n] = L[n];
    __syncthreads();
    if (n < N) {
        const int my = lvl[n];
        int pos = 0;
        for (int m = 0; m < N; ++m) {
            const int lm = lvl[m];
            pos += (int)((lm < my) | ((lm == my) & (m < n)));
        }
        dst[(size_t)b * N + n] = pos;
    }
}

// ---------------------------------------------------------------------------
// Kernel 2: crop_and_resize, one WAVE per (box, output row gi).
// Grid: (B*N, POOL), block: 64 threads (1 wave, no __syncthreads anywhere).
// Row pointers (ty/by) are fixed per wave; the 7 gj points are fully
// unrolled so up to 28 corner loads are outstanding simultaneously
// (R2 version had a serial 13-point loop with only 4 loads in flight).
//
// COORDINATE MATH IS DOUBLE PRECISION — the validity test `in_y <= H-1` is
// discontinuous and boxes clipped at 1.0 land within ulps of H-1; matching
// the np reference's f64 mask decisions requires bit-identical f64
// evaluation (same op order). Feature lerp stays f32. (Verified R2: absmax
// 454 -> 0.0156 with this scheme.)
// ---------------------------------------------------------------------------
__global__ __launch_bounds__(64) void roi_align_kernel(
    const float* __restrict__ boxes,
    const float* __restrict__ fm0, const float* __restrict__ fm1,
    const float* __restrict__ fm2, const float* __restrict__ fm3,
    const int* __restrict__ levels, const int* __restrict__ dst,
    float* __restrict__ out, int N, int C) {

    const int box_flat = blockIdx.x;
    const int gi   = blockIdx.y;       // output row 0..6
    const int lane = threadIdx.x;      // 0..63, lane*4 spans C=256
    const int b = box_flat / N;

    const int lv = levels[box_flat] - 1;  // 1..4 -> 0..3
    const float* fm; int S;
    if      (lv == 0) { fm = fm0; S = 256; }
    else if (lv == 1) { fm = fm1; S = 128; }
    else if (lv == 2) { fm = fm2; S = 64;  }
    else              { fm = fm3; S = 32;  }

    const double y1 = (double)boxes[(size_t)box_flat * 4 + 0];
    const double x1 = (double)boxes[(size_t)box_flat * 4 + 1];
    const double y2 = (double)boxes[(size_t)box_flat * 4 + 2];
    const double x2 = (double)boxes[(size_t)box_flat * 4 + 3];

    const double Hm1 = (double)(S - 1);
    const double sy = (y2 - y1) * Hm1 / (double)(POOL - 1);
    const double sx = (x2 - x1) * Hm1 / (double)(POOL - 1);

    // --- y (fixed for this wave) ---
    const double in_y = y1 * Hm1 + (double)gi * sy;
    const bool vy = (in_y >= 0.0) && (in_y <= Hm1);
    const double fy = floor(in_y);
    const float  wy = (float)(in_y - fy);
    const int ty = (int)fmin(fmax(fy, 0.0), Hm1);
    const int by = min(ty + 1, S - 1);

    const float* fmb  = fm + (size_t)b * S * S * C;
    const float* rowT = fmb + (size_t)ty * S * C;
    const float* rowB = fmb + (size_t)by * S * C;

    const int pos = dst[box_flat];
    float* orow = out + (((size_t)b * N + pos) * PP + (size_t)gi * POOL) * C
                      + lane * 4;

    const double ox = x1 * Hm1;
    const int c = lane * 4;

#pragma unroll
    for (int gj = 0; gj < POOL; ++gj) {
        const double in_x = ox + (double)gj * sx;
        const bool valid = vy && (in_x >= 0.0) && (in_x <= Hm1);

        float4 o;
        if (valid) {  // wave-uniform branch: free, skips loads when invalid
            const double fx = floor(in_x);
            const float  wx = (float)(in_x - fx);
            const int lx = (int)fmin(fmax(fx, 0.0), Hm1);
            const int rx = min(lx + 1, S - 1);

            const float4 tl = *(const float4*)(rowT + (size_t)lx * C + c);
            const float4 tr = *(const float4*)(rowT + (size_t)rx * C + c);
            const float4 bl = *(const float4*)(rowB + (size_t)lx * C + c);
            const float4 br = *(const float4*)(rowB + (size_t)rx * C + c);

            float top = tl.x + (tr.x - tl.x) * wx;
            float bot = bl.x + (br.x - bl.x) * wx;
            o.x = top + (bot - top) * wy;
            top = tl.y + (tr.y - tl.y) * wx;
            bot = bl.y + (br.y - bl.y) * wx;
            o.y = top + (bot - top) * wy;
            top = tl.z + (tr.z - tl.z) * wx;
            bot = bl.z + (br.z - bl.z) * wx;
            o.z = top + (bot - top) * wy;
            top = tl.w + (tr.w - tl.w) * wx;
            bot = bl.w + (br.w - bl.w) * wx;
            o.w = top + (bot - top) * wy;
        } else {
            o.x = 0.0f; o.y = 0.0f; o.z = 0.0f; o.w = 0.0f;
        }
        *(float4*)(orow + (size_t)gj * C) = o;
    }
}

extern "C" void kernel_launch(void* const* d_in, const int* in_sizes, int n_in,
                              void* d_out, int out_size, void* d_ws, size_t ws_size,
                              hipStream_t stream) {
    const float* boxes  = (const float*)d_in[0];
    const float* fm0    = (const float*)d_in[1];
    const float* fm1    = (const float*)d_in[2];
    const float* fm2    = (const float*)d_in[3];
    const float* fm3    = (const float*)d_in[4];
    const int*   levels = (const int*)d_in[5];
    float* out = (float*)d_out;

    const int BN = in_sizes[5];              // B*N = 2000
    const int C  = out_size / (BN * PP);     // 256
    const int B  = in_sizes[1] / (256 * 256 * C);  // fm0 is [B,256,256,C]
    const int N  = BN / B;                   // 1000

    int* dst = (int*)d_ws;                   // BN ints of scratch

    compute_order_kernel<<<B, 1024, 0, stream>>>(levels, dst, N);
    roi_align_kernel<<<dim3(BN, POOL), 64, 0, stream>>>(
        boxes, fm0, fm1, fm2, fm3, levels, dst, out, N, C);
}